// Round 13
// baseline (86.571 us; speedup 1.0000x reference)
//
#include <hip/hip_runtime.h>
#include <math.h>

#define HW 65536
#define NPX 524288      // 8*256*256
#define NEL 1572864     // 8*3*256*256

// ---- ws layout (float offsets); ws ~268MB, we use ~15MB ----
#define P_POINT 4096      // 3 x 2048  -> 10240
#define P_MS    10240     // 2 x 384   -> 11008
#define P_WIN   11008     // 3 x 512   -> 12544
#define P_FFT   12544     // 2 x 408   -> 13360
#define P_CURVE 13360     // 192 x 96  -> 31792
#define P_HIST  31792     // 384 x 64  -> 56368
#define R_SCAL  56368     // 5 scalars (e3, sL, sab, S2, S4)
#define R_CN    56384     // 3 x 96 = 288
#define R_HIST  56704     // 48 x 64 = 3072 -> 59776
#define MASK_OFF 65536    // 524288 floats
#define FFT_P   589824    // 24 slices * 66048 floats (256 rows x 129 cols float2)
#define FFT_T   (FFT_P + 24*66048)

#define CURVE_SCALE 131072.0f

// MEGA1 roles
#define B_POINT 2048
#define B_MS    384
#define B_CURVE 192
#define B_HIST  384
#define B_FFTR  1536          // 4 pair-FFTs (8 rows) per block
#define G_MEGA1 (B_POINT+B_MS+B_CURVE+B_HIST+B_FFTR)   // 4544
// MEGA2 roles
#define B_WIN   512
#define B_FFTC  408
#define B_RED   14            // 1 scalar + 1 curve + 12 hist reducers
#define G_MEGA2 (B_WIN+B_FFTC+B_RED)                    // 934

__device__ __forceinline__ float fpow24(float x) {
    return __builtin_amdgcn_exp2f(2.4f * __builtin_amdgcn_logf(x));
}
__device__ __forceinline__ float fcbrt(float x) {
    return __builtin_amdgcn_exp2f((1.0f/3.0f) * __builtin_amdgcn_logf(x));
}
__device__ __forceinline__ float labF(float t) {
    return t > 0.008856452f ? fcbrt(t) : t * 7.787037f + 0.13793103f;
}
__device__ __forceinline__ void rgb2lab(float r, float g, float b,
                                        float& L, float& A, float& Bc) {
    float lr = r > 0.04045f ? fpow24((r + 0.055f) * (1.0f/1.055f)) : r * (1.0f/12.92f);
    float lg = g > 0.04045f ? fpow24((g + 0.055f) * (1.0f/1.055f)) : g * (1.0f/12.92f);
    float lb = b > 0.04045f ? fpow24((b + 0.055f) * (1.0f/1.055f)) : b * (1.0f/12.92f);
    float X = (0.4124564f*lr + 0.3575761f*lg + 0.1804375f*lb) * (1.0f/0.95047f);
    float Y = (0.2126729f*lr + 0.7151522f*lg + 0.0721750f*lb);
    float Z = (0.0193339f*lr + 0.1191920f*lg + 0.9503041f*lb) * (1.0f/1.08883f);
    float fx = labF(X), fy = labF(Y), fz = labF(Z);
    L = 116.f*fy - 16.f;
    A = 500.f*(fx - fy);
    Bc = 200.f*(fy - fz);
}

__device__ __forceinline__ float blockSum(float v, float* sb) {
    #pragma unroll
    for (int o = 32; o > 0; o >>= 1) v += __shfl_down(v, o, 64);
    int lane = threadIdx.x & 63, w = threadIdx.x >> 6;
    if (lane == 0) sb[w] = v;
    __syncthreads();
    float r = 0.f;
    if (threadIdx.x == 0) {
        int nw = (blockDim.x + 63) >> 6;
        for (int i = 0; i < nw; ++i) r += sb[i];
    }
    __syncthreads();
    return r;
}

// ================= MEGA1: point | ms | curve | hist | pair-row-FFT =================
__global__ __launch_bounds__(256) void k_mega1(const float* __restrict__ pred,
                                               const float* __restrict__ targ,
                                               const float* __restrict__ inp,
                                               float* __restrict__ ws) {
    __shared__ __align__(16) unsigned char sm[17408];
    int tid = threadIdx.x;
    int bid = blockIdx.x;

    if (bid < B_POINT) {
        float* sb = (float*)sm;
        int i = bid*256 + tid;
        int b = i >> 16, hw = i & 65535;
        const float* p = pred + b*3*HW + hw;
        const float* t = targ + b*3*HW + hw;
        float pr = p[0], pg = p[HW], pb = p[2*HW];
        float tr = t[0], tg = t[HW], tb = t[2*HW];
        float e3 = fabsf(pr-tr) + fabsf(pg-tg) + fabsf(pb-tb);
        float Lp,Ap,Bp, Lt,At,Bt;
        rgb2lab(pr,pg,pb, Lp,Ap,Bp);
        rgb2lab(tr,tg,tb, Lt,At,Bt);
        float sL = fabsf(Lp-Lt);
        float sab = fabsf(Ap-At) + fabsf(Bp-Bt);
        float tmx = fmaxf(tr, fmaxf(tg, tb)), tmn = fminf(tr, fminf(tg, tb));
        float tsat = (tmx - tmn + 1e-7f) / (tmx + 1e-7f);
        ws[MASK_OFF + i] = (tmx > 0.6f && tsat > 0.2f) ? 1.f : 0.f;
        float v;
        v = blockSum(e3, sb);  if (tid == 0) ws[P_POINT + bid] = v;
        v = blockSum(sL, sb);  if (tid == 0) ws[P_POINT + 2048 + bid] = v;
        v = blockSum(sab, sb); if (tid == 0) ws[P_POINT + 4096 + bid] = v;
    } else if (bid < B_POINT + B_MS) {
        float* sb = (float*)sm;
        int blk = bid - B_POINT;
        int t = blk*256 + tid;
        int sc = t >> 12;
        int q = t & 4095;
        int y4 = q >> 6, x4 = q & 63;
        const float* pp = pred + sc*HW + (y4*4)*256 + x4*4;
        const float* tp = targ + sc*HW + (y4*4)*256 + x4*4;
        float4 p0 = *(const float4*)(pp);
        float4 p1 = *(const float4*)(pp + 256);
        float4 p2 = *(const float4*)(pp + 512);
        float4 p3 = *(const float4*)(pp + 768);
        float4 q0 = *(const float4*)(tp);
        float4 q1 = *(const float4*)(tp + 256);
        float4 q2 = *(const float4*)(tp + 512);
        float4 q3 = *(const float4*)(tp + 768);
        float a00 = (p0.x+p0.y+p1.x+p1.y)*0.25f, a01 = (p0.z+p0.w+p1.z+p1.w)*0.25f;
        float a10 = (p2.x+p2.y+p3.x+p3.y)*0.25f, a11 = (p2.z+p2.w+p3.z+p3.w)*0.25f;
        float b00 = (q0.x+q0.y+q1.x+q1.y)*0.25f, b01 = (q0.z+q0.w+q1.z+q1.w)*0.25f;
        float b10 = (q2.x+q2.y+q3.x+q3.y)*0.25f, b11 = (q2.z+q2.w+q3.z+q3.w)*0.25f;
        float s2 = fabsf(a00-b00)+fabsf(a01-b01)+fabsf(a10-b10)+fabsf(a11-b11);
        float s4 = fabsf((a00+a01+a10+a11)*0.25f - (b00+b01+b10+b11)*0.25f);
        float v;
        v = blockSum(s2, sb); if (tid == 0) ws[P_MS + blk] = v;
        v = blockSum(s4, sb); if (tid == 0) ws[P_MS + 384 + blk] = v;
    } else if (bid < B_POINT + B_MS + B_CURVE) {
        unsigned* h = (unsigned*)sm;       // 288
        if (tid < 256) h[tid] = 0u;
        if (tid < 32) h[256 + tid] = 0u;
        __syncthreads();
        int blk = bid - (B_POINT + B_MS);
        int slice = blk >> 3, part = blk & 7;
        int c = slice % 3;
        int base = slice * HW + part * 8192;
        const float4* ip = (const float4*)(inp + base);
        const float4* pp = (const float4*)(pred + base);
        const float4* tp = (const float4*)(targ + base);
        int segbase = 32 * c;
        #pragma unroll
        for (int it = 0; it < 8; ++it) {
            float4 a = ip[it*256 + tid];
            float4 p = pp[it*256 + tid];
            float4 t = tp[it*256 + tid];
            float av[4] = {a.x, a.y, a.z, a.w};
            float pv[4] = {p.x, p.y, p.z, p.w};
            float tv[4] = {t.x, t.y, t.z, t.w};
            #pragma unroll
            for (int j = 0; j < 4; ++j) {
                int idx = (int)(av[j] * 32.f);
                idx = min(max(idx, 0), 31);
                unsigned s3 = (unsigned)((segbase + idx) * 3);
                atomicAdd(&h[s3],     1u);
                atomicAdd(&h[s3 + 1], (unsigned)__float2uint_rn(pv[j] * CURVE_SCALE));
                atomicAdd(&h[s3 + 2], (unsigned)__float2uint_rn(tv[j] * CURVE_SCALE));
            }
        }
        __syncthreads();
        if (tid < 96) {
            unsigned v = h[segbase*3 + tid];
            int q = tid - (tid/3)*3;
            float f = (q == 0) ? (float)v : (float)v * (1.f/CURVE_SCALE);
            ws[P_CURVE + blk*96 + tid] = f;
        }
    } else if (bid < B_POINT + B_MS + B_CURVE + B_HIST) {
        // exact u32 fine-hist (1009 levels) + 193-tap Gaussian conv
        unsigned (*fh)[1024] = (unsigned(*)[1024])sm;
        float* wtab = (float*)(sm + 16384);
        int hb = bid - (B_POINT + B_MS + B_CURVE);
        int s = hb >> 3, part = hb & 7;
        const float* src = (s < 24 ? pred + s*HW : targ + (s-24)*HW) + part*8192;
        #pragma unroll
        for (int j = 0; j < 16; ++j) ((unsigned*)sm)[tid + 256*j] = 0u;
        if (tid < 193) {
            float d = (float)(tid - 96);
            wtab[tid] = __builtin_amdgcn_exp2f(-0.002907957f * d * d);
        }
        __syncthreads();
        int wv = tid >> 6;
        const float4* s4 = (const float4*)src;
        #pragma unroll
        for (int it = 0; it < 8; ++it) {
            float4 v = s4[it*256 + tid];
            float vals[4] = {v.x, v.y, v.z, v.w};
            #pragma unroll
            for (int e = 0; e < 4; ++e) {
                unsigned f = __float2uint_rn(vals[e] * 1008.f);
                f = min(f, 1008u);
                atomicAdd(&fh[wv][f], 1u);
            }
        }
        __syncthreads();
        #pragma unroll
        for (int j = 0; j < 4; ++j) {
            int idx = tid + 256*j;
            fh[0][idx] = fh[0][idx] + fh[1][idx] + fh[2][idx] + fh[3][idx];
        }
        __syncthreads();
        int k = tid >> 2, q = tid & 3;
        float acc = 0.f;
        for (int i = q; i < 193; i += 4) {
            int f = 16*k + i - 96;
            if (f >= 0 && f <= 1008) acc += (float)fh[0][f] * wtab[i];
        }
        acc += __shfl_xor(acc, 1, 64);
        acc += __shfl_xor(acc, 2, 64);
        if (q == 0) ws[P_HIST + hb*64 + k] = acc;
    } else {
        // ---- pair-row FFT: DIF (natural in, scrambled out), 4 pair-FFTs/block ----
        float (*re4)[256] = (float(*)[256])sm;                // 4 x 256
        float (*im4)[256] = (float(*)[256])(sm + 4096);       // 4 x 256
        int fb = bid - (B_POINT + B_MS + B_CURVE + B_HIST);   // 0..1535
        int fid = tid >> 6, l = tid & 63;
        int g = fb*4 + fid;                                   // 0..6143
        int s = g >> 7, pr = g & 127;                         // slice, row-pair
        const float* src = (s < 24 ? pred + s*HW : targ + (s-24)*HW) + (2*pr)*256;
        float* re = re4[fid];
        float* im = im4[fid];
        #pragma unroll
        for (int j = 0; j < 4; ++j) {
            int x = l + 64*j;
            re[x] = src[x];
            im[x] = src[256 + x];
        }
        __syncthreads();
        #pragma unroll
        for (int st = 0; st < 8; ++st) {
            int m = 256 >> st, half = m >> 1, sh = 7 - st;
            #pragma unroll
            for (int kk = 0; kk < 2; ++kk) {
                int bb = l + 64*kk;
                int j = bb & (half - 1);
                int i0 = ((bb >> sh) << (sh + 1)) + j;
                int i1 = i0 + half;
                float ang = -6.283185307f * (float)j / (float)m;
                float si, co;
                __sincosf(ang, &si, &co);
                float ur = re[i0], ui = im[i0];
                float vr = re[i1], vi = im[i1];
                re[i0] = ur + vr;
                im[i0] = ui + vi;
                float dr = ur - vr, di = ui - vi;
                re[i1] = dr*co - di*si;
                im[i1] = dr*si + di*co;
            }
            __syncthreads();
        }
        float2* outbase = (float2*)(ws + (s < 24 ? FFT_P + s*66048 : FFT_T + (s-24)*66048));
        float2* outA = outbase + (2*pr)*129;
        float2* outB = outbase + (2*pr+1)*129;
        #pragma unroll
        for (int kk = 0; kk < 2; ++kk) {
            int k = l + 64*kk;
            int kb  = __brev((unsigned)k) >> 24;
            int kmb = __brev((unsigned)((256 - k) & 255)) >> 24;
            float zr = re[kb], zi = im[kb];
            float wr = re[kmb], wi = im[kmb];
            outA[k] = make_float2(0.5f*(zr + wr), 0.5f*(zi - wi));
            outB[k] = make_float2(0.5f*(zi + wi), 0.5f*(wr - zr));
        }
        if (l == 0) {
            int kb = __brev(128u) >> 24;     // = 1
            float zr = re[kb], zi = im[kb];
            outA[128] = make_float2(zr, 0.f);
            outB[128] = make_float2(zi, 0.f);
        }
    }
}

// ================= MEGA2: win | col-FFT (DIF) | reducers =================
__global__ __launch_bounds__(256) void k_mega2(const float* __restrict__ pred,
                                               const float* __restrict__ targ,
                                               float* __restrict__ ws) {
    __shared__ __align__(16) unsigned char sm[33024];
    int tid = threadIdx.x;
    int bid = blockIdx.x;

    if (bid < B_WIN) {
        // ---- window boost: 4-row strip, separable 11x11 ----
        float (*msk)[256] = (float(*)[256])sm;                // 14 x 256
        float (*hs)[256]  = (float(*)[256])(sm + 14336);      // 14 x 256
        float* sb = (float*)(sm + 28672);
        int b = bid >> 6, strip = bid & 63;
        int y0 = strip * 4;
        int x = tid;
        const float* mbase = ws + MASK_OFF + b*HW;
        #pragma unroll
        for (int r = 0; r < 14; ++r) {
            int yy = y0 - 5 + r;
            msk[r][x] = (yy >= 0 && yy < 256) ? mbase[yy*256 + x] : 0.f;
        }
        __syncthreads();
        #pragma unroll
        for (int r = 0; r < 14; ++r) {
            float hsum = 0.f;
            #pragma unroll
            for (int dx = -5; dx <= 5; ++dx) {
                int xx = x + dx;
                if (xx >= 0 && xx < 256) hsum += msk[r][xx];
            }
            hs[r][x] = hsum;
        }
        __syncthreads();
        float acc_e3 = 0.f, acc_sd = 0.f, acc_m = 0.f;
        #pragma unroll
        for (int j = 0; j < 4; ++j) {
            int ry = y0 + j;
            float vs = 0.f;
            #pragma unroll
            for (int dy = 0; dy < 11; ++dy) vs += hs[j + dy][x];
            float m = vs * (1.f/121.f);
            const float* p = pred + b*3*HW + ry*256 + x;
            const float* t = targ + b*3*HW + ry*256 + x;
            float pr = p[0], pg = p[HW], pb = p[2*HW];
            float tr = t[0], tg = t[HW], tb = t[2*HW];
            float e3 = fabsf(pr-tr) + fabsf(pg-tg) + fabsf(pb-tb);
            float tmx = fmaxf(tr, fmaxf(tg, tb)), tmn = fminf(tr, fminf(tg, tb));
            float tsat = (tmx - tmn + 1e-7f) / (tmx + 1e-7f);
            float pmx = fmaxf(pr, fmaxf(pg, pb)), pmn = fminf(pr, fminf(pg, pb));
            float psat = (pmx - pmn + 1e-7f) / (pmx + 1e-7f);
            acc_e3 += e3 * m;
            acc_sd += fabsf(psat - tsat) * m;
            acc_m  += m;
        }
        float v;
        v = blockSum(acc_e3, sb); if (tid == 0) ws[P_WIN + bid] = v;
        v = blockSum(acc_sd, sb); if (tid == 0) ws[P_WIN + 512 + bid] = v;
        v = blockSum(acc_m,  sb); if (tid == 0) ws[P_WIN + 1024 + bid] = v;
    } else if (bid < B_WIN + B_FFTC) {
        // ---- col FFT (DIF, natural in, scrambled out; sum over all ky) ----
        float (*re_)[257] = (float(*)[257])sm;                  // 16 x 257
        float (*im_)[257] = (float(*)[257])(sm + 16448);        // 16 x 257
        float* sb = (float*)(sm + 32896);
        int cb = bid - B_WIN;                                   // 0..407
        int s = cb / 17, kt = cb - s*17;
        int k0 = kt * 8;
        const float2* srcP = (const float2*)(ws + FFT_P) + s*33024;
        const float2* srcT = (const float2*)(ws + FFT_T) + s*33024;
        int kk = tid & 7, r0 = tid >> 3;
        int col = k0 + kk;
        bool valid = (col <= 128);
        #pragma unroll
        for (int rb = 0; rb < 8; ++rb) {
            int r = r0 + rb*32;
            float2 vp = valid ? srcP[r*129 + col] : make_float2(0.f, 0.f);
            re_[kk][r] = vp.x; im_[kk][r] = vp.y;
            float2 vt = valid ? srcT[r*129 + col] : make_float2(0.f, 0.f);
            re_[8 + kk][r] = vt.x; im_[8 + kk][r] = vt.y;
        }
        __syncthreads();
        int fid = tid >> 4, w = tid & 15;
        float* re = re_[fid];
        float* im = im_[fid];
        #pragma unroll
        for (int st = 0; st < 8; ++st) {
            int m = 256 >> st, half = m >> 1, sh = 7 - st;
            #pragma unroll
            for (int q = 0; q < 8; ++q) {
                int bb = w + (q << 4);
                int j = bb & (half - 1);
                int i0 = ((bb >> sh) << (sh + 1)) + j;
                int i1 = i0 + half;
                float ang = -6.283185307f * (float)j / (float)m;
                float si, co;
                __sincosf(ang, &si, &co);
                float ur = re[i0], ui = im[i0];
                float vr = re[i1], vi = im[i1];
                re[i0] = ur + vr;
                im[i0] = ui + vi;
                float dr = ur - vr, di = ui - vi;
                re[i1] = dr*co - di*si;
                im[i1] = dr*si + di*co;
            }
            __syncthreads();
        }
        float d1 = 0.f, d2 = 0.f;
        #pragma unroll
        for (int e = 0; e < 8; ++e) {
            int idx = tid + e*256;
            int k = idx >> 8, r = idx & 255;
            if (k0 + k <= 128) {
                float pr2 = re_[k][r]*re_[k][r] + im_[k][r]*im_[k][r];
                float tr2 = re_[8+k][r]*re_[8+k][r] + im_[8+k][r]*im_[8+k][r];
                float d = fabsf(sqrtf(tr2) - sqrtf(pr2)) * (1.f/256.f);
                d1 += d; d2 += d*d;
            }
        }
        float v;
        v = blockSum(d1, sb); if (tid == 0) ws[P_FFT + cb] = v;
        v = blockSum(d2, sb); if (tid == 0) ws[P_FFT + 408 + cb] = v;
    } else {
        int rb = bid - (B_WIN + B_FFTC);   // 0..13
        if (rb == 0) {
            // scalar reducer: P_POINT (3x2048), P_MS (2x384) -> R_SCAL[0..4]
            float* sb = (float*)sm;
            float a0=0.f, a1=0.f, a2=0.f;
            for (int i = tid; i < 2048; i += 256) {
                a0 += ws[P_POINT + i];
                a1 += ws[P_POINT + 2048 + i];
                a2 += ws[P_POINT + 4096 + i];
            }
            float m0=0.f, m1=0.f;
            for (int i = tid; i < 384; i += 256) {
                m0 += ws[P_MS + i];
                m1 += ws[P_MS + 384 + i];
            }
            float v;
            v = blockSum(a0, sb); if (tid == 0) ws[R_SCAL + 0] = v;
            v = blockSum(a1, sb); if (tid == 0) ws[R_SCAL + 1] = v;
            v = blockSum(a2, sb); if (tid == 0) ws[R_SCAL + 2] = v;
            v = blockSum(m0, sb); if (tid == 0) ws[R_SCAL + 3] = v;
            v = blockSum(m1, sb); if (tid == 0) ws[R_SCAL + 4] = v;
        } else if (rb == 1) {
            // curve reducer: P_CURVE[192][96] -> R_CN[c*96 + j] (per-channel column sums)
            if (tid < 96) {
                float acc0 = 0.f, acc1 = 0.f, acc2 = 0.f;
                for (int r = 0; r < 192; ++r) {
                    int c = (r >> 3) % 3;          // uniform across lanes
                    float v = ws[P_CURVE + r*96 + tid];
                    if (c == 0) acc0 += v;
                    else if (c == 1) acc1 += v;
                    else acc2 += v;
                }
                ws[R_CN + tid]       = acc0;
                ws[R_CN + 96 + tid]  = acc1;
                ws[R_CN + 192 + tid] = acc2;
            }
        } else {
            // hist reducer: P_HIST[384][64] -> R_HIST[48][64]
            int h = rb - 2;                      // 0..11
            int s = h*4 + (tid >> 6), k = tid & 63;
            float acc = 0.f;
            #pragma unroll
            for (int p = 0; p < 8; ++p) acc += ws[P_HIST + (s*8 + p)*64 + k];
            ws[R_HIST + s*64 + k] = acc;
        }
    }
}

// ================= K_FINAL (small now) =================
__global__ __launch_bounds__(256) void k_final(const float* __restrict__ ws,
                                               float* __restrict__ out) {
    __shared__ float shist[3072];
    __shared__ float red[256];
    __shared__ float sb[8];
    int tid = threadIdx.x;
    for (int q = tid; q < 3072; q += 256) shist[q] = ws[R_HIST + q];
    float w0=0.f, w1=0.f, w2=0.f;
    for (int i = tid; i < 512; i += 256) {
        w0 += ws[P_WIN + i];
        w1 += ws[P_WIN + 512 + i];
        w2 += ws[P_WIN + 1024 + i];
    }
    float f0=0.f, f1=0.f;
    for (int i = tid; i < 408; i += 256) {
        f0 += ws[P_FFT + i];
        f1 += ws[P_FFT + 408 + i];
    }
    float wnum = blockSum(w0, sb);
    float wsat = blockSum(w1, sb);
    float wm   = blockSum(w2, sb);
    float d1   = blockSum(f0, sb);
    float d2   = blockSum(f1, sb);
    __syncthreads();
    // curve: seg (c,i) from per-channel column sums
    float cv = 0.f;
    if (tid < 96) {
        int c = tid >> 5, i = tid & 31;
        float cnt = ws[R_CN + c*96 + 3*i];
        float ps  = ws[R_CN + c*96 + 3*i + 1];
        float ts  = ws[R_CN + c*96 + 3*i + 2];
        if (cnt > 0.f) cv = fabsf(ps - ts) / cnt;
    }
    red[tid] = cv;
    __syncthreads();
    for (int o = 128; o > 0; o >>= 1) { if (tid < o) red[tid] += red[tid + o]; __syncthreads(); }
    float curve = red[0] / 96.f;
    __syncthreads();
    float hacc = 0.f;
    if (tid < 24) {
        const float* hp = shist + tid*64;
        const float* ht = shist + (24 + tid)*64;
        float sp = 0.f, stt = 0.f;
        for (int k = 0; k < 64; ++k) { sp += hp[k]; stt += ht[k]; }
        float ip = 1.f / (sp + 1e-7f), it = 1.f / (stt + 1e-7f);
        float cp = 0.f, ct = 0.f;
        for (int k = 0; k < 64; ++k) {
            cp += hp[k] * ip;
            ct += ht[k] * it;
            hacc += fabsf(cp - ct);
        }
    }
    red[tid] = hacc;
    __syncthreads();
    for (int o = 128; o > 0; o >>= 1) { if (tid < o) red[tid] += red[tid + o]; __syncthreads(); }
    float hl = red[0] / 1536.f;
    if (tid == 0) {
        float sum_e3 = ws[R_SCAL + 0];
        float sum_L  = ws[R_SCAL + 1];
        float sum_ab = ws[R_SCAL + 2];
        float S2     = ws[R_SCAL + 3];
        float S4     = ws[R_SCAL + 4];
        float l1  = sum_e3 / (float)NEL;
        float lab = (sum_L / (float)NPX) * 0.01f + 2.f * (sum_ab / (2.f * (float)NPX * 128.f));
        float ms  = (l1 + S2 / 393216.f + S4 / 98304.f) * (1.f/3.f);
        const float M = 792576.f;
        float ff  = (d2 / M) / (d1 / M + 1e-8f);
        float wb  = wnum / (wm*3.f + 1e-7f) + 0.5f * (wsat / (wm + 1e-7f));
        out[0] = l1 + 0.3f*ff + 0.4f*lab + 0.3f*ms + 0.4f*curve + 0.2f*hl + 0.5f*wb;
    }
}

extern "C" void kernel_launch(void* const* d_in, const int* in_sizes, int n_in,
                              void* d_out, int out_size, void* d_ws, size_t ws_size,
                              hipStream_t stream) {
    const float* pred = (const float*)d_in[0];
    const float* targ = (const float*)d_in[1];
    const float* inp  = (const float*)d_in[2];
    float* ws = (float*)d_ws;
    float* out = (float*)d_out;

    k_mega1<<<G_MEGA1, 256, 0, stream>>>(pred, targ, inp, ws);
    k_mega2<<<G_MEGA2, 256, 0, stream>>>(pred, targ, ws);
    k_final<<<1,       256, 0, stream>>>(ws, out);
}

// Round 14
// 61.620 us; speedup vs baseline: 1.4049x; 1.4049x over previous
//
#include <hip/hip_runtime.h>
#include <math.h>

#define HW 65536
#define NPX 524288      // 8*256*256
#define NEL 1572864     // 8*3*256*256

// ---- ws layout (float offsets); ws ~268MB, we use ~15MB ----
#define P_POINT 4096      // 3 x 2048  -> 10240
#define P_MS    10240     // 2 x 384   -> 11008
#define P_WIN   11008     // 3 x 512   -> 12544
#define P_FFT   12544     // 2 x 408   -> 13360
#define P_CURVE 13360     // 192 x 96  -> 31792
#define P_HIST  31792     // 384 x 64  -> 56368
#define MASK_OFF 65536    // 524288 floats
#define FFT_P   589824    // 24 slices * 66048 floats (256 rows x 129 cols float2)
#define FFT_T   (FFT_P + 24*66048)

#define CURVE_SCALE 131072.0f

// MEGA1 roles
#define B_POINT 2048
#define B_MS    384
#define B_CURVE 192
#define B_HIST  384
#define B_FFTR  1536          // 4 pair-FFTs (8 rows) per block
#define G_MEGA1 (B_POINT+B_MS+B_CURVE+B_HIST+B_FFTR)   // 4544
// MEGA2 roles
#define B_WIN   512
#define B_FFTC  408
#define G_MEGA2 (B_WIN+B_FFTC)                          // 920

__device__ __forceinline__ float fpow24(float x) {
    return __builtin_amdgcn_exp2f(2.4f * __builtin_amdgcn_logf(x));
}
__device__ __forceinline__ float fcbrt(float x) {
    return __builtin_amdgcn_exp2f((1.0f/3.0f) * __builtin_amdgcn_logf(x));
}
__device__ __forceinline__ float labF(float t) {
    return t > 0.008856452f ? fcbrt(t) : t * 7.787037f + 0.13793103f;
}
__device__ __forceinline__ void rgb2lab(float r, float g, float b,
                                        float& L, float& A, float& Bc) {
    float lr = r > 0.04045f ? fpow24((r + 0.055f) * (1.0f/1.055f)) : r * (1.0f/12.92f);
    float lg = g > 0.04045f ? fpow24((g + 0.055f) * (1.0f/1.055f)) : g * (1.0f/12.92f);
    float lb = b > 0.04045f ? fpow24((b + 0.055f) * (1.0f/1.055f)) : b * (1.0f/12.92f);
    float X = (0.4124564f*lr + 0.3575761f*lg + 0.1804375f*lb) * (1.0f/0.95047f);
    float Y = (0.2126729f*lr + 0.7151522f*lg + 0.0721750f*lb);
    float Z = (0.0193339f*lr + 0.1191920f*lg + 0.9503041f*lb) * (1.0f/1.08883f);
    float fx = labF(X), fy = labF(Y), fz = labF(Z);
    L = 116.f*fy - 16.f;
    A = 500.f*(fx - fy);
    Bc = 200.f*(fy - fz);
}

__device__ __forceinline__ float blockSum(float v, float* sb) {
    #pragma unroll
    for (int o = 32; o > 0; o >>= 1) v += __shfl_down(v, o, 64);
    int lane = threadIdx.x & 63, w = threadIdx.x >> 6;
    if (lane == 0) sb[w] = v;
    __syncthreads();
    float r = 0.f;
    if (threadIdx.x == 0) {
        int nw = (blockDim.x + 63) >> 6;
        for (int i = 0; i < nw; ++i) r += sb[i];
    }
    __syncthreads();
    return r;
}

// ================= MEGA1: point | ms | curve | hist | pair-row-FFT =================
__global__ __launch_bounds__(256) void k_mega1(const float* __restrict__ pred,
                                               const float* __restrict__ targ,
                                               const float* __restrict__ inp,
                                               float* __restrict__ ws) {
    __shared__ __align__(16) unsigned char sm[17408];
    int tid = threadIdx.x;
    int bid = blockIdx.x;

    if (bid < B_POINT) {
        float* sb = (float*)sm;
        int i = bid*256 + tid;
        int b = i >> 16, hw = i & 65535;
        const float* p = pred + b*3*HW + hw;
        const float* t = targ + b*3*HW + hw;
        float pr = p[0], pg = p[HW], pb = p[2*HW];
        float tr = t[0], tg = t[HW], tb = t[2*HW];
        float e3 = fabsf(pr-tr) + fabsf(pg-tg) + fabsf(pb-tb);
        float Lp,Ap,Bp, Lt,At,Bt;
        rgb2lab(pr,pg,pb, Lp,Ap,Bp);
        rgb2lab(tr,tg,tb, Lt,At,Bt);
        float sL = fabsf(Lp-Lt);
        float sab = fabsf(Ap-At) + fabsf(Bp-Bt);
        float tmx = fmaxf(tr, fmaxf(tg, tb)), tmn = fminf(tr, fminf(tg, tb));
        float tsat = (tmx - tmn + 1e-7f) / (tmx + 1e-7f);
        ws[MASK_OFF + i] = (tmx > 0.6f && tsat > 0.2f) ? 1.f : 0.f;
        float v;
        v = blockSum(e3, sb);  if (tid == 0) ws[P_POINT + bid] = v;
        v = blockSum(sL, sb);  if (tid == 0) ws[P_POINT + 2048 + bid] = v;
        v = blockSum(sab, sb); if (tid == 0) ws[P_POINT + 4096 + bid] = v;
    } else if (bid < B_POINT + B_MS) {
        float* sb = (float*)sm;
        int blk = bid - B_POINT;
        int t = blk*256 + tid;
        int sc = t >> 12;
        int q = t & 4095;
        int y4 = q >> 6, x4 = q & 63;
        const float* pp = pred + sc*HW + (y4*4)*256 + x4*4;
        const float* tp = targ + sc*HW + (y4*4)*256 + x4*4;
        float4 p0 = *(const float4*)(pp);
        float4 p1 = *(const float4*)(pp + 256);
        float4 p2 = *(const float4*)(pp + 512);
        float4 p3 = *(const float4*)(pp + 768);
        float4 q0 = *(const float4*)(tp);
        float4 q1 = *(const float4*)(tp + 256);
        float4 q2 = *(const float4*)(tp + 512);
        float4 q3 = *(const float4*)(tp + 768);
        float a00 = (p0.x+p0.y+p1.x+p1.y)*0.25f, a01 = (p0.z+p0.w+p1.z+p1.w)*0.25f;
        float a10 = (p2.x+p2.y+p3.x+p3.y)*0.25f, a11 = (p2.z+p2.w+p3.z+p3.w)*0.25f;
        float b00 = (q0.x+q0.y+q1.x+q1.y)*0.25f, b01 = (q0.z+q0.w+q1.z+q1.w)*0.25f;
        float b10 = (q2.x+q2.y+q3.x+q3.y)*0.25f, b11 = (q2.z+q2.w+q3.z+q3.w)*0.25f;
        float s2 = fabsf(a00-b00)+fabsf(a01-b01)+fabsf(a10-b10)+fabsf(a11-b11);
        float s4 = fabsf((a00+a01+a10+a11)*0.25f - (b00+b01+b10+b11)*0.25f);
        float v;
        v = blockSum(s2, sb); if (tid == 0) ws[P_MS + blk] = v;
        v = blockSum(s4, sb); if (tid == 0) ws[P_MS + 384 + blk] = v;
    } else if (bid < B_POINT + B_MS + B_CURVE) {
        unsigned* h = (unsigned*)sm;       // 288
        if (tid < 256) h[tid] = 0u;
        if (tid < 32) h[256 + tid] = 0u;
        __syncthreads();
        int blk = bid - (B_POINT + B_MS);
        int slice = blk >> 3, part = blk & 7;
        int c = slice % 3;
        int base = slice * HW + part * 8192;
        const float4* ip = (const float4*)(inp + base);
        const float4* pp = (const float4*)(pred + base);
        const float4* tp = (const float4*)(targ + base);
        int segbase = 32 * c;
        #pragma unroll
        for (int it = 0; it < 8; ++it) {
            float4 a = ip[it*256 + tid];
            float4 p = pp[it*256 + tid];
            float4 t = tp[it*256 + tid];
            float av[4] = {a.x, a.y, a.z, a.w};
            float pv[4] = {p.x, p.y, p.z, p.w};
            float tv[4] = {t.x, t.y, t.z, t.w};
            #pragma unroll
            for (int j = 0; j < 4; ++j) {
                int idx = (int)(av[j] * 32.f);
                idx = min(max(idx, 0), 31);
                unsigned s3 = (unsigned)((segbase + idx) * 3);
                atomicAdd(&h[s3],     1u);
                atomicAdd(&h[s3 + 1], (unsigned)__float2uint_rn(pv[j] * CURVE_SCALE));
                atomicAdd(&h[s3 + 2], (unsigned)__float2uint_rn(tv[j] * CURVE_SCALE));
            }
        }
        __syncthreads();
        if (tid < 96) {
            unsigned v = h[segbase*3 + tid];
            int q = tid - (tid/3)*3;
            float f = (q == 0) ? (float)v : (float)v * (1.f/CURVE_SCALE);
            ws[P_CURVE + blk*96 + tid] = f;
        }
    } else if (bid < B_POINT + B_MS + B_CURVE + B_HIST) {
        // exact u32 fine-hist (1009 levels) + 193-tap Gaussian conv
        unsigned (*fh)[1024] = (unsigned(*)[1024])sm;
        float* wtab = (float*)(sm + 16384);
        int hb = bid - (B_POINT + B_MS + B_CURVE);
        int s = hb >> 3, part = hb & 7;
        const float* src = (s < 24 ? pred + s*HW : targ + (s-24)*HW) + part*8192;
        #pragma unroll
        for (int j = 0; j < 16; ++j) ((unsigned*)sm)[tid + 256*j] = 0u;
        if (tid < 193) {
            float d = (float)(tid - 96);
            wtab[tid] = __builtin_amdgcn_exp2f(-0.002907957f * d * d);
        }
        __syncthreads();
        int wv = tid >> 6;
        const float4* s4 = (const float4*)src;
        #pragma unroll
        for (int it = 0; it < 8; ++it) {
            float4 v = s4[it*256 + tid];
            float vals[4] = {v.x, v.y, v.z, v.w};
            #pragma unroll
            for (int e = 0; e < 4; ++e) {
                unsigned f = __float2uint_rn(vals[e] * 1008.f);
                f = min(f, 1008u);
                atomicAdd(&fh[wv][f], 1u);
            }
        }
        __syncthreads();
        #pragma unroll
        for (int j = 0; j < 4; ++j) {
            int idx = tid + 256*j;
            fh[0][idx] = fh[0][idx] + fh[1][idx] + fh[2][idx] + fh[3][idx];
        }
        __syncthreads();
        int k = tid >> 2, q = tid & 3;
        float acc = 0.f;
        for (int i = q; i < 193; i += 4) {
            int f = 16*k + i - 96;
            if (f >= 0 && f <= 1008) acc += (float)fh[0][f] * wtab[i];
        }
        acc += __shfl_xor(acc, 1, 64);
        acc += __shfl_xor(acc, 2, 64);
        if (q == 0) ws[P_HIST + hb*64 + k] = acc;
    } else {
        // ---- pair-row FFT: DIF (natural in, scrambled out), 4 pair-FFTs/block ----
        float (*re4)[256] = (float(*)[256])sm;                // 4 x 256
        float (*im4)[256] = (float(*)[256])(sm + 4096);       // 4 x 256
        int fb = bid - (B_POINT + B_MS + B_CURVE + B_HIST);   // 0..1535
        int fid = tid >> 6, l = tid & 63;
        int g = fb*4 + fid;                                   // 0..6143
        int s = g >> 7, pr = g & 127;                         // slice, row-pair
        const float* src = (s < 24 ? pred + s*HW : targ + (s-24)*HW) + (2*pr)*256;
        float* re = re4[fid];
        float* im = im4[fid];
        #pragma unroll
        for (int j = 0; j < 4; ++j) {
            int x = l + 64*j;
            re[x] = src[x];
            im[x] = src[256 + x];
        }
        __syncthreads();
        #pragma unroll
        for (int st = 0; st < 8; ++st) {
            int m = 256 >> st, half = m >> 1, sh = 7 - st;
            #pragma unroll
            for (int kk = 0; kk < 2; ++kk) {
                int bb = l + 64*kk;
                int j = bb & (half - 1);
                int i0 = ((bb >> sh) << (sh + 1)) + j;
                int i1 = i0 + half;
                float ang = -6.283185307f * (float)j / (float)m;
                float si, co;
                __sincosf(ang, &si, &co);
                float ur = re[i0], ui = im[i0];
                float vr = re[i1], vi = im[i1];
                re[i0] = ur + vr;
                im[i0] = ui + vi;
                float dr = ur - vr, di = ui - vi;
                re[i1] = dr*co - di*si;
                im[i1] = dr*si + di*co;
            }
            __syncthreads();
        }
        float2* outbase = (float2*)(ws + (s < 24 ? FFT_P + s*66048 : FFT_T + (s-24)*66048));
        float2* outA = outbase + (2*pr)*129;
        float2* outB = outbase + (2*pr+1)*129;
        #pragma unroll
        for (int kk = 0; kk < 2; ++kk) {
            int k = l + 64*kk;
            int kb  = __brev((unsigned)k) >> 24;
            int kmb = __brev((unsigned)((256 - k) & 255)) >> 24;
            float zr = re[kb], zi = im[kb];
            float wr = re[kmb], wi = im[kmb];
            outA[k] = make_float2(0.5f*(zr + wr), 0.5f*(zi - wi));
            outB[k] = make_float2(0.5f*(zi + wi), 0.5f*(wr - zr));
        }
        if (l == 0) {
            int kb = __brev(128u) >> 24;     // = 1
            float zr = re[kb], zi = im[kb];
            outA[128] = make_float2(zr, 0.f);
            outB[128] = make_float2(zi, 0.f);
        }
    }
}

// ================= MEGA2: win | col-FFT (DIF, padded LDS) =================
__global__ __launch_bounds__(256) void k_mega2(const float* __restrict__ pred,
                                               const float* __restrict__ targ,
                                               float* __restrict__ ws) {
    __shared__ __align__(16) unsigned char sm[34880];
    int tid = threadIdx.x;
    int bid = blockIdx.x;

    if (bid < B_WIN) {
        // ---- window boost: 4-row strip, separable 11x11 ----
        float (*msk)[256] = (float(*)[256])sm;                // 14 x 256
        float (*hs)[256]  = (float(*)[256])(sm + 14336);      // 14 x 256
        float* sb = (float*)(sm + 28672);
        int b = bid >> 6, strip = bid & 63;
        int y0 = strip * 4;
        int x = tid;
        const float* mbase = ws + MASK_OFF + b*HW;
        #pragma unroll
        for (int r = 0; r < 14; ++r) {
            int yy = y0 - 5 + r;
            msk[r][x] = (yy >= 0 && yy < 256) ? mbase[yy*256 + x] : 0.f;
        }
        __syncthreads();
        #pragma unroll
        for (int r = 0; r < 14; ++r) {
            float hsum = 0.f;
            #pragma unroll
            for (int dx = -5; dx <= 5; ++dx) {
                int xx = x + dx;
                if (xx >= 0 && xx < 256) hsum += msk[r][xx];
            }
            hs[r][x] = hsum;
        }
        __syncthreads();
        float acc_e3 = 0.f, acc_sd = 0.f, acc_m = 0.f;
        #pragma unroll
        for (int j = 0; j < 4; ++j) {
            int ry = y0 + j;
            float vs = 0.f;
            #pragma unroll
            for (int dy = 0; dy < 11; ++dy) vs += hs[j + dy][x];
            float m = vs * (1.f/121.f);
            const float* p = pred + b*3*HW + ry*256 + x;
            const float* t = targ + b*3*HW + ry*256 + x;
            float pr = p[0], pg = p[HW], pb = p[2*HW];
            float tr = t[0], tg = t[HW], tb = t[2*HW];
            float e3 = fabsf(pr-tr) + fabsf(pg-tg) + fabsf(pb-tb);
            float tmx = fmaxf(tr, fmaxf(tg, tb)), tmn = fminf(tr, fminf(tg, tb));
            float tsat = (tmx - tmn + 1e-7f) / (tmx + 1e-7f);
            float pmx = fmaxf(pr, fmaxf(pg, pb)), pmn = fminf(pr, fminf(pg, pb));
            float psat = (pmx - pmn + 1e-7f) / (pmx + 1e-7f);
            acc_e3 += e3 * m;
            acc_sd += fabsf(psat - tsat) * m;
            acc_m  += m;
        }
        float v;
        v = blockSum(acc_e3, sb); if (tid == 0) ws[P_WIN + bid] = v;
        v = blockSum(acc_sd, sb); if (tid == 0) ws[P_WIN + 512 + bid] = v;
        v = blockSum(acc_m,  sb); if (tid == 0) ws[P_WIN + 1024 + bid] = v;
    } else {
        // ---- col FFT (DIF; LDS rows padded to 272 floats: stride%32==16 -> 2-way only) ----
        float (*re_)[272] = (float(*)[272])sm;                  // 16 x 272
        float (*im_)[272] = (float(*)[272])(sm + 17408);        // 16 x 272
        float* sb = (float*)(sm + 34816);
        int cb = bid - B_WIN;                                   // 0..407
        int s = cb / 17, kt = cb - s*17;
        int k0 = kt * 8;
        const float2* srcP = (const float2*)(ws + FFT_P) + s*33024;
        const float2* srcT = (const float2*)(ws + FFT_T) + s*33024;
        int kk = tid & 7, r0 = tid >> 3;
        int col = k0 + kk;
        bool valid = (col <= 128);
        #pragma unroll
        for (int rb = 0; rb < 8; ++rb) {
            int r = r0 + rb*32;
            float2 vp = valid ? srcP[r*129 + col] : make_float2(0.f, 0.f);
            re_[kk][r] = vp.x; im_[kk][r] = vp.y;
            float2 vt = valid ? srcT[r*129 + col] : make_float2(0.f, 0.f);
            re_[8 + kk][r] = vt.x; im_[8 + kk][r] = vt.y;
        }
        __syncthreads();
        int fid = tid >> 4, w = tid & 15;
        float* re = re_[fid];
        float* im = im_[fid];
        #pragma unroll
        for (int st = 0; st < 8; ++st) {
            int m = 256 >> st, half = m >> 1, sh = 7 - st;
            #pragma unroll
            for (int q = 0; q < 8; ++q) {
                int bb = w + (q << 4);
                int j = bb & (half - 1);
                int i0 = ((bb >> sh) << (sh + 1)) + j;
                int i1 = i0 + half;
                float ang = -6.283185307f * (float)j / (float)m;
                float si, co;
                __sincosf(ang, &si, &co);
                float ur = re[i0], ui = im[i0];
                float vr = re[i1], vi = im[i1];
                re[i0] = ur + vr;
                im[i0] = ui + vi;
                float dr = ur - vr, di = ui - vi;
                re[i1] = dr*co - di*si;
                im[i1] = dr*si + di*co;
            }
            __syncthreads();
        }
        float d1 = 0.f, d2 = 0.f;
        #pragma unroll
        for (int e = 0; e < 8; ++e) {
            int idx = tid + e*256;
            int k = idx >> 8, r = idx & 255;
            if (k0 + k <= 128) {
                float pr2 = re_[k][r]*re_[k][r] + im_[k][r]*im_[k][r];
                float tr2 = re_[8+k][r]*re_[8+k][r] + im_[8+k][r]*im_[8+k][r];
                float d = fabsf(sqrtf(tr2) - sqrtf(pr2)) * (1.f/256.f);
                d1 += d; d2 += d*d;
            }
        }
        float v;
        v = blockSum(d1, sb); if (tid == 0) ws[P_FFT + cb] = v;
        v = blockSum(d2, sb); if (tid == 0) ws[P_FFT + 408 + cb] = v;
    }
}

// ================= K_FINAL =================
__global__ __launch_bounds__(256) void k_final(const float* __restrict__ ws,
                                               float* __restrict__ out) {
    __shared__ float shist[3072];
    __shared__ float scn[288];
    __shared__ float red[256];
    __shared__ float sb[8];
    int tid = threadIdx.x;
    // hist pre-reduce: 3072 slice-bins x 8 parts (coalesced)
    for (int q = tid; q < 3072; q += 256) {
        int s = q >> 6, k = q & 63;
        float t = 0.f;
        const float* base = ws + P_HIST + s*8*64 + k;
        #pragma unroll
        for (int p = 0; p < 8; ++p) t += base[p*64];
        shist[q] = t;
    }
    // curve pre-reduce: 288 (channel, column) sums over 64 rows each, all threads
    for (int pj = tid; pj < 288; pj += 256) {
        int c = pj / 96, j = pj - c*96;
        float acc = 0.f;
        #pragma unroll
        for (int t = 0; t < 8; ++t) {
            const float* base = ws + P_CURVE + (8*c + 24*t)*96 + j;
            #pragma unroll
            for (int p = 0; p < 8; ++p) acc += base[p*96];
        }
        scn[pj] = acc;
    }
    // scalar partial reductions
    float a0=0.f, a1=0.f, a2=0.f;
    for (int i = tid; i < 2048; i += 256) {
        a0 += ws[P_POINT + i];
        a1 += ws[P_POINT + 2048 + i];
        a2 += ws[P_POINT + 4096 + i];
    }
    float w0=0.f, w1=0.f, w2=0.f;
    for (int i = tid; i < 512; i += 256) {
        w0 += ws[P_WIN + i];
        w1 += ws[P_WIN + 512 + i];
        w2 += ws[P_WIN + 1024 + i];
    }
    float m0=0.f, m1=0.f;
    for (int i = tid; i < 384; i += 256) {
        m0 += ws[P_MS + i];
        m1 += ws[P_MS + 384 + i];
    }
    float f0=0.f, f1=0.f;
    for (int i = tid; i < 408; i += 256) {
        f0 += ws[P_FFT + i];
        f1 += ws[P_FFT + 408 + i];
    }
    float sum_e3 = blockSum(a0, sb);
    float sum_L  = blockSum(a1, sb);
    float sum_ab = blockSum(a2, sb);
    float wnum   = blockSum(w0, sb);
    float wsat   = blockSum(w1, sb);
    float wm     = blockSum(w2, sb);
    float S2     = blockSum(m0, sb);
    float S4     = blockSum(m1, sb);
    float d1     = blockSum(f0, sb);
    float d2     = blockSum(f1, sb);
    __syncthreads();
    // curve: seg (c,i) from per-channel column sums in LDS
    float cv = 0.f;
    if (tid < 96) {
        int c = tid >> 5, i = tid & 31;
        float cnt = scn[c*96 + 3*i];
        float ps  = scn[c*96 + 3*i + 1];
        float ts  = scn[c*96 + 3*i + 2];
        if (cnt > 0.f) cv = fabsf(ps - ts) / cnt;
    }
    red[tid] = cv;
    __syncthreads();
    for (int o = 128; o > 0; o >>= 1) { if (tid < o) red[tid] += red[tid + o]; __syncthreads(); }
    float curve = red[0] / 96.f;
    __syncthreads();
    float hacc = 0.f;
    if (tid < 24) {
        const float* hp = shist + tid*64;
        const float* ht = shist + (24 + tid)*64;
        float sp = 0.f, stt = 0.f;
        for (int k = 0; k < 64; ++k) { sp += hp[k]; stt += ht[k]; }
        float ip = 1.f / (sp + 1e-7f), it = 1.f / (stt + 1e-7f);
        float cp = 0.f, ct = 0.f;
        for (int k = 0; k < 64; ++k) {
            cp += hp[k] * ip;
            ct += ht[k] * it;
            hacc += fabsf(cp - ct);
        }
    }
    red[tid] = hacc;
    __syncthreads();
    for (int o = 128; o > 0; o >>= 1) { if (tid < o) red[tid] += red[tid + o]; __syncthreads(); }
    float hl = red[0] / 1536.f;
    if (tid == 0) {
        float l1  = sum_e3 / (float)NEL;
        float lab = (sum_L / (float)NPX) * 0.01f + 2.f * (sum_ab / (2.f * (float)NPX * 128.f));
        float ms  = (l1 + S2 / 393216.f + S4 / 98304.f) * (1.f/3.f);
        const float M = 792576.f;
        float ff  = (d2 / M) / (d1 / M + 1e-8f);
        float wb  = wnum / (wm*3.f + 1e-7f) + 0.5f * (wsat / (wm + 1e-7f));
        out[0] = l1 + 0.3f*ff + 0.4f*lab + 0.3f*ms + 0.4f*curve + 0.2f*hl + 0.5f*wb;
    }
}

extern "C" void kernel_launch(void* const* d_in, const int* in_sizes, int n_in,
                              void* d_out, int out_size, void* d_ws, size_t ws_size,
                              hipStream_t stream) {
    const float* pred = (const float*)d_in[0];
    const float* targ = (const float*)d_in[1];
    const float* inp  = (const float*)d_in[2];
    float* ws = (float*)d_ws;
    float* out = (float*)d_out;

    k_mega1<<<G_MEGA1, 256, 0, stream>>>(pred, targ, inp, ws);
    k_mega2<<<G_MEGA2, 256, 0, stream>>>(pred, targ, ws);
    k_final<<<1,       256, 0, stream>>>(ws, out);
}